// Round 9
// baseline (290.967 us; speedup 1.0000x reference)
//
#include <hip/hip_runtime.h>
#include <hip/hip_bf16.h>
#include <stdint.h>

#define BATCH 8
#define SEQ   2048
#define DIM   1024

typedef unsigned short u16;
typedef __attribute__((ext_vector_type(8))) short short8;
typedef __attribute__((ext_vector_type(4))) float f32x4;
typedef __attribute__((ext_vector_type(4))) unsigned short us4;

__device__ __forceinline__ u16 f2bf(float x){
  union { float f; uint32_t u; } c; c.f = x;
  uint32_t u = c.u;
  uint32_t r = u + 0x7fffu + ((u >> 16) & 1u);
  return (u16)(r >> 16);
}
__device__ __forceinline__ float bf2f(u16 s){
  union { uint32_t u; float f; } c; c.u = ((uint32_t)s) << 16;
  return c.f;
}

__device__ __forceinline__ void gload16(const void* g, void* l){
  __builtin_amdgcn_global_load_lds(
      (const __attribute__((address_space(1))) void*)g,
      (__attribute__((address_space(3))) void*)l, 16, 0, 0);
}

__device__ __forceinline__ f32x4 mfma3(short8 ah, short8 al, short8 bh, short8 bl, f32x4 c){
  c = __builtin_amdgcn_mfma_f32_16x16x32_bf16(ah, bh, c, 0,0,0);
  c = __builtin_amdgcn_mfma_f32_16x16x32_bf16(ah, bl, c, 0,0,0);
  c = __builtin_amdgcn_mfma_f32_16x16x32_bf16(al, bh, c, 0,0,0);
  return c;
}

// ---------- split fp32 [R][1024] -> u16 [R][2048] rows packed [hi|lo] ----------
__global__ __launch_bounds__(256) void k_split(const float* __restrict__ src,
                                               u16* __restrict__ dst, int nchunk){
  for (int i = blockIdx.x*blockDim.x + threadIdx.x; i < nchunk; i += gridDim.x*blockDim.x){
    int r = i >> 8;
    int c = (i & 255) << 2;
    f32x4 v = *(const f32x4*)(src + (size_t)r*DIM + c);
    us4 h, l;
    #pragma unroll
    for (int j = 0; j < 4; j++){
      u16 hh = f2bf(v[j]);
      h[j] = hh;
      l[j] = f2bf(v[j] - bf2f(hh));
    }
    u16* d = dst + (size_t)r*(2*DIM) + c;
    *(us4*)d         = h;
    *(us4*)(d + DIM) = l;
  }
}

// ---------- transpose + split (K and V in one launch): z<8 -> K->Kt, z>=8 -> V->Vt ----------
__global__ __launch_bounds__(256) void k_convert_kv(const float* __restrict__ K,
                                                    const float* __restrict__ V,
                                                    u16* __restrict__ Kt,
                                                    u16* __restrict__ Vt){
  __shared__ float tile[64][65];
  int z = blockIdx.z;
  const float* Src = (z < 8 ? K : V);
  u16* Dst = (z < 8 ? Kt : Vt);
  int zb = z & 7;
  const float* Vb = Src + (size_t)zb * SEQ * DIM;
  u16* Vtb = Dst + (size_t)zb * DIM * (2*SEQ);
  int s0 = blockIdx.x * 64, d0 = blockIdx.y * 64;
  int t = threadIdx.x;
  int rs = t >> 4;
  int cd = (t & 15) * 4;
  #pragma unroll
  for (int i = 0; i < 4; i++){
    int s = rs + i*16;
    f32x4 v = *(const f32x4*)(Vb + (size_t)(s0 + s)*DIM + d0 + cd);
    tile[s][cd+0] = v[0]; tile[s][cd+1] = v[1];
    tile[s][cd+2] = v[2]; tile[s][cd+3] = v[3];
  }
  __syncthreads();
  int dl = t >> 4;
  int sl = (t & 15) * 4;
  #pragma unroll
  for (int i = 0; i < 4; i++){
    int d = dl + i*16;
    us4 h, l;
    #pragma unroll
    for (int j = 0; j < 4; j++){
      float x = tile[sl+j][d];
      u16 hh = f2bf(x);
      h[j] = hh;
      l[j] = f2bf(x - bf2f(hh));
    }
    size_t off = (size_t)(d0 + d) * (2*SEQ) + s0 + sl;
    *(us4*)(Vtb + off)       = h;
    *(us4*)(Vtb + off + SEQ) = l;
  }
}

// ---------- BMx256 4-wave big-tile GEMM, hi/lo split, in-wave ILP ----------
// 4 waves (2x2), wave tile (BM/2)x128. No intra-tile barriers: compiler's
// fine lgkmcnt hides the wave's own ds_reads under its own MFMAs.
// A: [M][2*KROW] u16 [hi|lo]; B: [Nrows][2*KROW]. K per block = KROW.
// SPLITOUT=1: C = acc/32 split u16 [M][2*NOUT]; SPLITOUT=0: C = acc fp32 [M][NOUT].
template<int BM, int KROW, int SPLITOUT, int NOUT, int TPZX, int TPZY>
__global__ __launch_bounds__(256,1) void k_gemm4(const u16* __restrict__ A,
                                                 const u16* __restrict__ B,
                                                 void* __restrict__ Cout,
                                                 size_t aStride, size_t bStride, size_t cStride){
  constexpr int LA  = 2*KROW;
  constexpr int NT  = KROW/32;          // K-tiles
  constexpr int AF  = BM/32;            // A frags per wave (4 or 8)
  constexpr int NAG = AF/4;             // A groups of 4 frags
  constexpr int ACH = BM/64;            // A 64-row staging chunks per array
  constexpr int NLD = 2*ACH + 8;        // gloads per thread per K-tile
  constexpr int OAL = BM*32;            // LDS elem offsets per buf
  constexpr int OBH = 2*BM*32;
  constexpr int OBL = 2*BM*32 + 8192;
  constexpr int LDSPB = 2*BM*32 + 16384;

  __shared__ __align__(16) u16 lds[2][LDSPB];

  int xcd = blockIdx.x & 7;
  int idx = blockIdx.x >> 3;
  int nPerX = gridDim.x >> 3;
  int gid = xcd * nPerX + idx;
  constexpr int TPZ = TPZX*TPZY;
  int z  = gid / TPZ;
  int rm = gid % TPZ;
  int bx = rm % TPZX;
  int by = rm / TPZX;

  const u16* Ab = A + (size_t)z * aStride;
  const u16* Bb = B + (size_t)z * bStride;

  int t0 = threadIdx.x, lane = t0 & 63, wv = t0 >> 6;
  int wm = (wv >> 1) * (BM/2);
  int wn = (wv & 1) * 128;
  int fr = lane & 15;
  int rdSlot = ((lane >> 4) ^ ((fr >> 1) & 3)) * 8;
  int srow4 = lane >> 2;                               // 0..15
  int srcSlot = ((lane & 3) ^ ((lane >> 3) & 3)) * 8;  // pre-swizzled source slot

  const u16* aB = Ab + ((size_t)bx*BM)  * LA + srcSlot;
  const u16* bB = Bb + ((size_t)by*256) * LA + srcSlot;

  f32x4 acc[AF][8] = {};
  short8 aH[4], aL[4], bH[4], bL[4];

  #define STAGE(buf, t32)                                                     \
    { size_t kof = (size_t)(t32)*32;                                          \
      _Pragma("unroll")                                                       \
      for (int c = 0; c < ACH; c++){                                          \
        size_t ro = (size_t)(c*64 + wv*16 + srow4)*LA + kof;                  \
        gload16(aB + ro,        &lds[buf][      c*2048 + wv*512]);            \
        gload16(aB + KROW + ro, &lds[buf][OAL + c*2048 + wv*512]);            \
      }                                                                       \
      _Pragma("unroll")                                                       \
      for (int c = 0; c < 4; c++){                                            \
        size_t ro = (size_t)(c*64 + wv*16 + srow4)*LA + kof;                  \
        gload16(bB + ro,        &lds[buf][OBH + c*2048 + wv*512]);            \
        gload16(bB + KROW + ro, &lds[buf][OBL + c*2048 + wv*512]);            \
      } }

  #define LOAD_A(buf, ag)                                                     \
    { _Pragma("unroll")                                                       \
      for (int q = 0; q < 4; q++){                                            \
        int ra = (wm + (ag)*64 + q*16 + fr)*32 + rdSlot;                      \
        aH[q] = *(const short8*)&lds[buf][ra];                                \
        aL[q] = *(const short8*)&lds[buf][OAL + ra];                          \
      } }
  #define LOAD_B(buf, bh)                                                     \
    { _Pragma("unroll")                                                       \
      for (int q = 0; q < 4; q++){                                            \
        int rb = (wn + (bh)*64 + q*16 + fr)*32 + rdSlot;                      \
        bH[q] = *(const short8*)&lds[buf][OBH + rb];                          \
        bL[q] = *(const short8*)&lds[buf][OBL + rb];                          \
      } }
  #define MFMA_BLK(ag, bh)                                                    \
    { _Pragma("unroll")                                                       \
      for (int q = 0; q < 4; q++){                                            \
        _Pragma("unroll")                                                     \
        for (int j = 0; j < 4; j++){                                          \
          acc[(ag)*4+q][(bh)*4+j] =                                           \
            mfma3(aH[q], aL[q], bH[j], bL[j], acc[(ag)*4+q][(bh)*4+j]);       \
        } } }

  #define SB0() __builtin_amdgcn_sched_barrier(0)

  STAGE(0, 0)
  asm volatile("s_waitcnt vmcnt(0)" ::: "memory");
  __builtin_amdgcn_s_barrier();
  SB0();

  for (int t = 0; t < NT; t++){
    int buf = t & 1;
    if (t+1 < NT){
      STAGE(buf^1, t+1)
      asm volatile("s_waitcnt vmcnt(%0)" :: "i"(NLD) : "memory");  // tile-t landed
    } else {
      asm volatile("s_waitcnt vmcnt(0)" ::: "memory");
    }
    __builtin_amdgcn_s_barrier();
    SB0();
    // in-wave ILP compute: no barriers, compiler-interleaved ds_read/MFMA
    #pragma unroll
    for (int bh = 0; bh < 2; bh++){
      LOAD_B(buf, bh)
      #pragma unroll
      for (int ag = 0; ag < NAG; ag++){
        LOAD_A(buf, ag)
        MFMA_BLK(ag, bh)
      }
    }
    SB0();
    __builtin_amdgcn_s_barrier();   // all reads of buf done -> next STAGE may overwrite
    SB0();
  }

  #undef STAGE
  #undef LOAD_A
  #undef LOAD_B
  #undef MFMA_BLK
  #undef SB0

  int cr = (lane >> 4) * 4;
  if (SPLITOUT){
    u16* Cb = (u16*)Cout + (size_t)z * cStride;
    const float scale = 0.03125f;   // 1/sqrt(1024)
    #pragma unroll
    for (int mi = 0; mi < AF; mi++){
      int gr = bx*BM + wm + mi*16 + cr;
      #pragma unroll
      for (int ni = 0; ni < 8; ni++){
        int gc = by*256 + wn + ni*16 + fr;
        #pragma unroll
        for (int e = 0; e < 4; e++){
          float x = acc[mi][ni][e] * scale;
          u16 h = f2bf(x);
          u16 l = f2bf(x - bf2f(h));
          size_t off = (size_t)(gr + e) * (2*NOUT) + gc;
          Cb[off]        = h;
          Cb[off + NOUT] = l;
        }
      }
    }
  } else {
    float* Cb = (float*)Cout + (size_t)z * cStride;
    #pragma unroll
    for (int mi = 0; mi < AF; mi++){
      int gr = bx*BM + wm + mi*16 + cr;
      #pragma unroll
      for (int ni = 0; ni < 8; ni++){
        int gc = by*256 + wn + ni*16 + fr;
        #pragma unroll
        for (int e = 0; e < 4; e++)
          Cb[(size_t)(gr + e) * NOUT + gc] = acc[mi][ni][e];
      }
    }
  }
}

// ---------- row softmax over D=1024, in place on d_out ----------
__global__ __launch_bounds__(256) void k_softmax(float* __restrict__ O){
  float* p = O + (size_t)blockIdx.x * DIM;
  int t = threadIdx.x;
  int lane = t & 63, wave = t >> 6;
  f32x4 v = *(f32x4*)(p + t*4);
  float m = fmaxf(fmaxf(v[0], v[1]), fmaxf(v[2], v[3]));
  #pragma unroll
  for (int o = 32; o > 0; o >>= 1) m = fmaxf(m, __shfl_xor(m, o));
  __shared__ float rmax[4], rsum[4];
  if (lane == 0) rmax[wave] = m;
  __syncthreads();
  m = fmaxf(fmaxf(rmax[0], rmax[1]), fmaxf(rmax[2], rmax[3]));
  float e0 = expf(v[0]-m), e1 = expf(v[1]-m), e2 = expf(v[2]-m), e3 = expf(v[3]-m);
  float s = e0 + e1 + e2 + e3;
  #pragma unroll
  for (int o = 32; o > 0; o >>= 1) s += __shfl_xor(s, o);
  if (lane == 0) rsum[wave] = s;
  __syncthreads();
  s = rsum[0] + rsum[1] + rsum[2] + rsum[3];
  float inv = 1.0f / s;
  f32x4 rv = { e0*inv, e1*inv, e2*inv, e3*inv };
  *(f32x4*)(p + t*4) = rv;
}

extern "C" void kernel_launch(void* const* d_in, const int* in_sizes, int n_in,
                              void* d_out, int out_size, void* d_ws, size_t ws_size,
                              hipStream_t stream){
  const float* Q = (const float*)d_in[0];
  const float* K = (const float*)d_in[1];
  const float* V = (const float*)d_in[2];
  float* Out = (float*)d_out;
  u16* w = (u16*)d_ws;

  const size_t QsB = (size_t)SEQ * (2*DIM);
  const size_t KtB = (size_t)DIM * (2*SEQ);
  const size_t VtB = KtB;
  const size_t WsB = (size_t)DIM * (2*DIM);

  dim3 blk(256);
  dim3 cgrid(SEQ/64, DIM/64, 16);

  const size_t need = 8 * (KtB + VtB + WsB) * sizeof(u16);   // ~167.8 MB

  if (ws_size >= need){
    u16* Kt = w;
    u16* Vt = Kt + 8*KtB;
    u16* Ws = Vt + 8*VtB;
    u16* Qs = w;                         // reuses Kt/Vt region after GEMM-A (stream-ordered)
    k_convert_kv<<<cgrid, blk, 0, stream>>>(K, V, Kt, Vt);
    // GEMM-A: Ws = (Vt . Kt^T)/32 -> split u16 [1024][2048]/batch. 256 blocks, K=2048.
    k_gemm4<128, SEQ, 1, DIM, 8, 4><<<dim3(256), blk, 0, stream>>>(
        Vt, Kt, Ws, VtB, KtB, WsB);
    k_split<<<dim3(2048), blk, 0, stream>>>(Q, Qs, 8*SEQ*(DIM/4));
    // GEMM-B: Out = Qs . Ws^T -> fp32 [2048][1024]/batch. 256 blocks, K=1024.
    k_gemm4<256, DIM, 0, DIM, 8, 4><<<dim3(256), blk, 0, stream>>>(
        Qs, Ws, Out, QsB, WsB, (size_t)SEQ*DIM);
  } else {
    // per-batch fallback
    u16* Qs = w;
    u16* Kt = Qs + QsB;
    u16* Vt = Kt + KtB;
    u16* Ws = Vt + VtB;
    for (int b = 0; b < BATCH; b++){
      const size_t inOff = (size_t)b * SEQ * DIM;
      k_split<<<dim3(1024), blk, 0, stream>>>(Q + inOff, Qs, SEQ*(DIM/4));
      k_convert_kv<<<dim3(SEQ/64, DIM/64, 1), blk, 0, stream>>>(K + inOff, K + inOff, Kt, Kt);
      k_convert_kv<<<dim3(SEQ/64, DIM/64, 1), blk, 0, stream>>>(V + inOff, V + inOff, Vt, Vt);
      k_gemm4<128, SEQ, 1, DIM, 8, 4><<<dim3(32), blk, 0, stream>>>(
          Vt, Kt, Ws, VtB, KtB, WsB);
      k_gemm4<256, DIM, 0, DIM, 8, 4><<<dim3(32), blk, 0, stream>>>(
          Qs, Ws, Out + inOff, QsB, WsB, (size_t)SEQ*DIM);
    }
  }
  k_softmax<<<dim3(BATCH*SEQ), blk, 0, stream>>>(Out);
}